// Round 4
// baseline (218.125 us; speedup 1.0000x reference)
//
#include <hip/hip_runtime.h>

// 25 qubits, DIM=2, targets (10, 3) on a row-major (2,)*25 array.
// Axis t has element stride 2^(24-t):
//   axis 10 -> stride 2^14 (gate index 'a')
//   axis 3  -> stride 2^21 (gate index 'b')
// Gate op[a, b, a', b'] flat index = a*8 + b*4 + a'*2 + b'.
// out[base + a*2^14 + b*2^21] = sum_{a',b'} M[a,b,a',b'] * in[base + a'*2^14 + b'*2^21]
// Complex split: outR = Mr*xr - Mi*xi ; outI = Mr*xi + Mi*xr.
//
// R3 -> R4: 8 groups/thread (2x float4 per stream) — halve per-byte
// instruction overhead, double in-flight bytes per wave. Nontemporal kept.

#define N_STATE  (1u << 25)
#define S_A      (1u << 14)   // stride of target axis 10
#define S_B      (1u << 21)   // stride of target axis 3

typedef float v4f __attribute__((ext_vector_type(4)));

__global__ __launch_bounds__(256)
void gate2q_kernel(const float* __restrict__ qs_r,
                   const float* __restrict__ qs_i,
                   const float* __restrict__ m_r,
                   const float* __restrict__ m_i,
                   float* __restrict__ out_r,
                   float* __restrict__ out_i)
{
    float Mr[16], Mi[16];
#pragma unroll
    for (int k = 0; k < 16; ++k) { Mr[k] = m_r[k]; Mi[k] = m_i[k]; }

    unsigned t = blockIdx.x * blockDim.x + threadIdx.x;   // [0, 2^20)
    unsigned g = t << 3;                                  // group index, 8-aligned
    // Insert zero bit at position 14, then at position 21 -> base has bits 14,21 clear.
    unsigned y    = ((g >> 14) << 15) | (g & 0x3FFFu);
    unsigned base = ((y >> 21) << 22) | (y & 0x1FFFFFu);

    // 4 paired streams x {real, imag} x 2 float4s each = 32 x 16B in flight.
    v4f xr[4][2], xi[4][2];
#pragma unroll
    for (int ap = 0; ap < 2; ++ap) {
#pragma unroll
        for (int bp = 0; bp < 2; ++bp) {
            unsigned off = base + ap * S_A + bp * S_B;
            int s = ap * 2 + bp;
            xr[s][0] = __builtin_nontemporal_load(reinterpret_cast<const v4f*>(qs_r + off));
            xr[s][1] = __builtin_nontemporal_load(reinterpret_cast<const v4f*>(qs_r + off + 4));
            xi[s][0] = __builtin_nontemporal_load(reinterpret_cast<const v4f*>(qs_i + off));
            xi[s][1] = __builtin_nontemporal_load(reinterpret_cast<const v4f*>(qs_i + off + 4));
        }
    }

#pragma unroll
    for (int a = 0; a < 2; ++a) {
#pragma unroll
        for (int b = 0; b < 2; ++b) {
#pragma unroll
            for (int h = 0; h < 2; ++h) {
                v4f oR = (v4f)(0.f);
                v4f oI = (v4f)(0.f);
#pragma unroll
                for (int ap = 0; ap < 2; ++ap) {
#pragma unroll
                    for (int bp = 0; bp < 2; ++bp) {
                        int   mi = a * 8 + b * 4 + ap * 2 + bp;
                        float mr = Mr[mi];
                        float mm = Mi[mi];
                        v4f r = xr[ap * 2 + bp][h];
                        v4f q = xi[ap * 2 + bp][h];
                        oR += mr * r - mm * q;
                        oI += mr * q + mm * r;
                    }
                }
                unsigned off = base + a * S_A + b * S_B + h * 4;
                __builtin_nontemporal_store(oR, reinterpret_cast<v4f*>(out_r + off));
                __builtin_nontemporal_store(oI, reinterpret_cast<v4f*>(out_i + off));
            }
        }
    }
}

extern "C" void kernel_launch(void* const* d_in, const int* in_sizes, int n_in,
                              void* d_out, int out_size, void* d_ws, size_t ws_size,
                              hipStream_t stream) {
    const float* qs_r = (const float*)d_in[0];
    const float* qs_i = (const float*)d_in[1];
    const float* m_r  = (const float*)d_in[2];
    const float* m_i  = (const float*)d_in[3];

    float* out_r = (float*)d_out;            // out_real: 2^25 floats
    float* out_i = out_r + N_STATE;          // out_imag: 2^25 floats

    const unsigned n_threads = N_STATE / 4 / 8;  // 2^20: 8 groups of 4 amps per thread
    const unsigned block = 256;
    const unsigned grid  = n_threads / block;    // 4096 blocks

    gate2q_kernel<<<grid, block, 0, stream>>>(qs_r, qs_i, m_r, m_i, out_r, out_i);
}

// Round 5
// 97.021 us; speedup vs baseline: 2.2482x; 2.2482x over previous
//
#include <hip/hip_runtime.h>

// 25 qubits, DIM=2, targets (10, 3) on a row-major (2,)*25 array.
// Axis t has element stride 2^(24-t):
//   axis 10 -> stride 2^14 (gate index 'a')
//   axis 3  -> stride 2^21 (gate index 'b')
// Gate op[a, b, a', b'] flat index = a*8 + b*4 + a'*2 + b'.
// out[base + a*2^14 + b*2^21] = sum_{a',b'} M[a,b,a',b'] * in[base + a'*2^14 + b'*2^21]
// Complex split: outR = Mr*xr - Mi*xi ; outI = Mr*xi + Mi*xr.
//
// R4 -> R5: R4's 2-float4-per-thread layout broke store coalescing
// (16B writes at 32B stride => WRITE_SIZE 2x, 218us). Redo the MLP
// experiment with TWO lane-contiguous 4-group chunks per thread
// (chunk1 = chunk0 + 256 threads) so every instruction stays unit-stride.

#define N_STATE  (1u << 25)
#define S_A      (1u << 14)   // stride of target axis 10
#define S_B      (1u << 21)   // stride of target axis 3

typedef float v4f __attribute__((ext_vector_type(4)));

__device__ __forceinline__ unsigned group_base(unsigned g) {
    unsigned y = ((g >> 14) << 15) | (g & 0x3FFFu);
    return ((y >> 21) << 22) | (y & 0x1FFFFFu);
}

__global__ __launch_bounds__(256)
void gate2q_kernel(const float* __restrict__ qs_r,
                   const float* __restrict__ qs_i,
                   const float* __restrict__ m_r,
                   const float* __restrict__ m_i,
                   float* __restrict__ out_r,
                   float* __restrict__ out_i)
{
    float Mr[16], Mi[16];
#pragma unroll
    for (int k = 0; k < 16; ++k) { Mr[k] = m_r[k]; Mi[k] = m_i[k]; }

    // Two lane-contiguous chunks: u and u+256 (same block, +1024 groups*4 floats).
    unsigned u = blockIdx.x * (blockDim.x * 2) + threadIdx.x;  // [0, 2^21) stepped
    unsigned base0 = group_base(u << 2);
    unsigned base1 = group_base((u + 256) << 2);

    // Issue all 16 loads up front: 4 paired streams x {r,i} x 2 chunks.
    v4f xr[2][4], xi[2][4];
#pragma unroll
    for (int ap = 0; ap < 2; ++ap) {
#pragma unroll
        for (int bp = 0; bp < 2; ++bp) {
            int s = ap * 2 + bp;
            unsigned o0 = base0 + ap * S_A + bp * S_B;
            unsigned o1 = base1 + ap * S_A + bp * S_B;
            xr[0][s] = __builtin_nontemporal_load(reinterpret_cast<const v4f*>(qs_r + o0));
            xi[0][s] = __builtin_nontemporal_load(reinterpret_cast<const v4f*>(qs_i + o0));
            xr[1][s] = __builtin_nontemporal_load(reinterpret_cast<const v4f*>(qs_r + o1));
            xi[1][s] = __builtin_nontemporal_load(reinterpret_cast<const v4f*>(qs_i + o1));
        }
    }

#pragma unroll
    for (int c = 0; c < 2; ++c) {
        unsigned base = c ? base1 : base0;
#pragma unroll
        for (int a = 0; a < 2; ++a) {
#pragma unroll
            for (int b = 0; b < 2; ++b) {
                v4f oR = (v4f)(0.f);
                v4f oI = (v4f)(0.f);
#pragma unroll
                for (int ap = 0; ap < 2; ++ap) {
#pragma unroll
                    for (int bp = 0; bp < 2; ++bp) {
                        int   mi = a * 8 + b * 4 + ap * 2 + bp;
                        float mr = Mr[mi];
                        float mm = Mi[mi];
                        v4f r = xr[c][ap * 2 + bp];
                        v4f q = xi[c][ap * 2 + bp];
                        oR += mr * r - mm * q;
                        oI += mr * q + mm * r;
                    }
                }
                unsigned off = base + a * S_A + b * S_B;
                __builtin_nontemporal_store(oR, reinterpret_cast<v4f*>(out_r + off));
                __builtin_nontemporal_store(oI, reinterpret_cast<v4f*>(out_i + off));
            }
        }
    }
}

extern "C" void kernel_launch(void* const* d_in, const int* in_sizes, int n_in,
                              void* d_out, int out_size, void* d_ws, size_t ws_size,
                              hipStream_t stream) {
    const float* qs_r = (const float*)d_in[0];
    const float* qs_i = (const float*)d_in[1];
    const float* m_r  = (const float*)d_in[2];
    const float* m_i  = (const float*)d_in[3];

    float* out_r = (float*)d_out;            // out_real: 2^25 floats
    float* out_i = out_r + N_STATE;          // out_imag: 2^25 floats

    const unsigned n_threads = N_STATE / 4 / 8;  // 2^20 threads, 8 groups each
    const unsigned block = 256;
    const unsigned grid  = n_threads / block;    // 4096 blocks

    gate2q_kernel<<<grid, block, 0, stream>>>(qs_r, qs_i, m_r, m_i, out_r, out_i);
}

// Round 6
// 93.913 us; speedup vs baseline: 2.3226x; 1.0331x over previous
//
#include <hip/hip_runtime.h>

// 25 qubits, DIM=2, targets (10, 3) on a row-major (2,)*25 array.
// Axis t has element stride 2^(24-t):
//   axis 10 -> stride 2^14 (gate index 'a')
//   axis 3  -> stride 2^21 (gate index 'b')
// Gate op[a, b, a', b'] flat index = a*8 + b*4 + a'*2 + b'.
// out[base + a*2^14 + b*2^21] = sum_{a',b'} M[a,b,a',b'] * in[base + a'*2^14 + b'*2^21]
// Complex split: outR = Mr*xr - Mi*xi ; outI = Mr*xi + Mi*xr.
//
// FINAL (revert to R3 config — best measured 94.2 us, 5.70 TB/s):
//  - 4 groups (one float4 per stream) per thread, every instruction
//    lane-contiguous 1 KB per wave.
//  - nontemporal loads/stores: 512 MB zero-reuse working set > L3;
//    cache bypass recovered 7% (101.5 -> 94.2 us).
//  - 8-groups/thread MLP variant measured WORSE (97.0 us): DRAM-limited,
//    not issue-limited. 2x-float4-per-thread variant broke write
//    coalescing (218 us). Do not revisit either.

#define N_STATE  (1u << 25)
#define S_A      (1u << 14)   // stride of target axis 10
#define S_B      (1u << 21)   // stride of target axis 3

typedef float v4f __attribute__((ext_vector_type(4)));

__global__ __launch_bounds__(256)
void gate2q_kernel(const float* __restrict__ qs_r,
                   const float* __restrict__ qs_i,
                   const float* __restrict__ m_r,
                   const float* __restrict__ m_i,
                   float* __restrict__ out_r,
                   float* __restrict__ out_i)
{
    // Gate matrix into registers (uniform address -> scalar loads, L2-hit).
    float Mr[16], Mi[16];
#pragma unroll
    for (int k = 0; k < 16; ++k) { Mr[k] = m_r[k]; Mi[k] = m_i[k]; }

    unsigned t = blockIdx.x * blockDim.x + threadIdx.x;   // [0, 2^21)
    unsigned g = t << 2;                                  // group index, 4-aligned
    // Insert zero bit at position 14, then at position 21 -> base has bits 14,21 clear.
    unsigned y    = ((g >> 14) << 15) | (g & 0x3FFFu);
    unsigned base = ((y >> 21) << 22) | (y & 0x1FFFFFu);

    // Load the 4 paired streams, real+imag, 16B each, nontemporal.
    v4f xr[4], xi[4];
#pragma unroll
    for (int ap = 0; ap < 2; ++ap) {
#pragma unroll
        for (int bp = 0; bp < 2; ++bp) {
            unsigned off = base + ap * S_A + bp * S_B;
            xr[ap * 2 + bp] = __builtin_nontemporal_load(
                reinterpret_cast<const v4f*>(qs_r + off));
            xi[ap * 2 + bp] = __builtin_nontemporal_load(
                reinterpret_cast<const v4f*>(qs_i + off));
        }
    }

#pragma unroll
    for (int a = 0; a < 2; ++a) {
#pragma unroll
        for (int b = 0; b < 2; ++b) {
            v4f oR = (v4f)(0.f);
            v4f oI = (v4f)(0.f);
#pragma unroll
            for (int ap = 0; ap < 2; ++ap) {
#pragma unroll
                for (int bp = 0; bp < 2; ++bp) {
                    int   mi = a * 8 + b * 4 + ap * 2 + bp;
                    float mr = Mr[mi];
                    float mm = Mi[mi];
                    v4f r = xr[ap * 2 + bp];
                    v4f q = xi[ap * 2 + bp];
                    oR += mr * r - mm * q;
                    oI += mr * q + mm * r;
                }
            }
            unsigned off = base + a * S_A + b * S_B;
            __builtin_nontemporal_store(oR, reinterpret_cast<v4f*>(out_r + off));
            __builtin_nontemporal_store(oI, reinterpret_cast<v4f*>(out_i + off));
        }
    }
}

extern "C" void kernel_launch(void* const* d_in, const int* in_sizes, int n_in,
                              void* d_out, int out_size, void* d_ws, size_t ws_size,
                              hipStream_t stream) {
    const float* qs_r = (const float*)d_in[0];
    const float* qs_i = (const float*)d_in[1];
    const float* m_r  = (const float*)d_in[2];
    const float* m_i  = (const float*)d_in[3];

    float* out_r = (float*)d_out;            // out_real: 2^25 floats
    float* out_i = out_r + N_STATE;          // out_imag: 2^25 floats

    const unsigned n_threads = N_STATE / 4 / 4;  // 2^21: 4 groups of 4 amps per thread
    const unsigned block = 256;
    const unsigned grid  = n_threads / block;    // 8192 blocks

    gate2q_kernel<<<grid, block, 0, stream>>>(qs_r, qs_i, m_r, m_i, out_r, out_i);
}